// Round 8
// baseline (272.107 us; speedup 1.0000x reference)
//
#include <hip/hip_runtime.h>
#include <hip/hip_bf16.h>

typedef __attribute__((ext_vector_type(4))) float f32x4;
typedef __attribute__((ext_vector_type(8))) short bf16x8;
typedef __attribute__((ext_vector_type(4))) unsigned u32x4;

#define DEV static __device__ __forceinline__

DEV int imin(int a, int b) { return a < b ? a : b; }

DEV short f2bf(float f) {
  union { float f; unsigned u; } v; v.f = f;
  unsigned r = (v.u + 0x7fffu + ((v.u >> 16) & 1u)) >> 16;
  return (short)r;
}

DEV unsigned pkbf(float lo, float hi) {
  unsigned r;
  asm("v_cvt_pk_bf16_f32 %0, %1, %2" : "=v"(r) : "v"(lo), "v"(hi));
  return r;
}

DEV bf16x8 cvt8(const float* __restrict__ p) {
  f32x4 a = *reinterpret_cast<const f32x4*>(p);
  f32x4 b = *reinterpret_cast<const f32x4*>(p + 4);
  bf16x8 r;
  r[0] = f2bf(a[0]); r[1] = f2bf(a[1]); r[2] = f2bf(a[2]); r[3] = f2bf(a[3]);
  r[4] = f2bf(b[0]); r[5] = f2bf(b[1]); r[6] = f2bf(b[2]); r[7] = f2bf(b[3]);
  return r;
}

// kslot->element permutation shared by {P,V} (keys) and {Q,K} (d):
// sigma(s) = ((s&4)<<2) | ((s>>3)<<2) | (s&3)
DEV int sigma(int s) { return ((s & 4) << 2) | ((s >> 3) << 2) | (s & 3); }

// ---------------------------------------------------------------------------
// K1: depthwise 3x3 on skip -> dwQ bf16 [b][pix(4096)][c(128)]
// grid (64 y, 4 c-quarters, 8 b) = 2048 blocks, 256 thr.
// ---------------------------------------------------------------------------
__global__ __launch_bounds__(256) void k_dwq(const float* __restrict__ skip,
    const float* __restrict__ dw_q, short* __restrict__ dwQ) {
  const int b = blockIdx.z, cq = blockIdx.y, y = blockIdx.x;
  __shared__ __align__(16) short T[64][40];  // [x][32 c], pad 8
  const int t = threadIdx.x;
  {
    const int x = t & 63, cg = t >> 6;
    #pragma unroll
    for (int i = 0; i < 8; ++i) {
      const int cl = cg * 8 + i;
      const int c = cq * 32 + cl;
      const float* sp = skip + (b * 128 + c) * 4096;
      const float* wp = dw_q + c * 9;
      float acc = 0.f;
      #pragma unroll
      for (int ky = 0; ky < 3; ++ky) {
        const int yy = y + ky - 1;
        if (yy < 0 || yy > 63) continue;
        #pragma unroll
        for (int kx = 0; kx < 3; ++kx) {
          const int xx = x + kx - 1;
          if (xx < 0 || xx > 63) continue;
          acc += sp[yy * 64 + xx] * wp[ky * 3 + kx];
        }
      }
      T[x][cl] = f2bf(acc);
    }
  }
  __syncthreads();
  const int x2 = t >> 2, cc = t & 3;
  bf16x8 v = *reinterpret_cast<const bf16x8*>(&T[x2][cc * 8]);
  *reinterpret_cast<bf16x8*>(dwQ + (b * 4096 + y * 64 + x2) * 128 + cq * 32 + cc * 8) = v;
}

// ---------------------------------------------------------------------------
// K2: kv16 = pw_kv( dw3x3(x) )  f32 [b][o(256)][pix(256)]
// grid (16 rows, 2 o-halves, 8 b) = 256 blocks, 512 thr (8 waves x 16 o).
// dw phase duplicated per o-half (runs on different CUs -> more parallelism).
// ---------------------------------------------------------------------------
__global__ __launch_bounds__(512) void k_kvgen(const float* __restrict__ x,
    const float* __restrict__ dw_kv, const float* __restrict__ pw_kv,
    float* __restrict__ kv16) {
  const int b = blockIdx.z;
  const int oh = blockIdx.y;
  const int pq = blockIdx.x;  // image row (16 pixels)
  __shared__ __align__(16) short dwxT[16][264];
  const int t = threadIdx.x;
  {
    const int pl = t & 15;
    const int cg = t >> 4;  // 32 groups of 8 channels
    const int py = pq, px = pl;
    #pragma unroll
    for (int i = 0; i < 8; ++i) {
      const int c = cg * 8 + i;
      const float* sp = x + (b * 256 + c) * 256;
      const float* wp = dw_kv + c * 9;
      float acc = 0.f;
      #pragma unroll
      for (int ky = 0; ky < 3; ++ky) {
        const int yy = py + ky - 1;
        if (yy < 0 || yy > 15) continue;
        #pragma unroll
        for (int kx = 0; kx < 3; ++kx) {
          const int xx = px + kx - 1;
          if (xx < 0 || xx > 15) continue;
          acc += sp[yy * 16 + xx] * wp[ky * 3 + kx];
        }
      }
      dwxT[pl][c] = f2bf(acc);
    }
  }
  __syncthreads();
  const int w = t >> 6, l = t & 63, lr = l & 15, lg = l >> 4;
  f32x4 acc = f32x4{0.f, 0.f, 0.f, 0.f};
  const int o = oh * 128 + w * 16 + lr;  // A-row for this lane
  #pragma unroll
  for (int kk = 0; kk < 8; ++kk) {
    const int c0 = kk * 32 + lg * 8;
    bf16x8 bfr = *reinterpret_cast<const bf16x8*>(&dwxT[lr][c0]);
    bf16x8 afr = cvt8(pw_kv + o * 256 + c0);
    acc = __builtin_amdgcn_mfma_f32_16x16x32_bf16(afr, bfr, acc, 0, 0, 0);
  }
  #pragma unroll
  for (int r = 0; r < 4; ++r) {
    const int oo = oh * 128 + w * 16 + lg * 4 + r;
    kv16[(b * 256 + oo) * 256 + pq * 16 + lr] = acc[r];
  }
}

// ---------------------------------------------------------------------------
// K3: bilinear resize 16x16 -> 32x32 (align_corners), split k/v, with the
// sigma permutation baked in:
//   Kp bf16 [bh][key(1024)][pos(32)]  where pos holds d = sigma(pos)
//   Vp bf16 [bh][d(32)][kb(32)][pos(32)] where pos holds key kb*32+sigma(pos)
// ---------------------------------------------------------------------------
DEV float bilin16(const float* __restrict__ p, int key) {
  const int oy = key >> 5, ox = key & 31;
  const float s = 15.f / 31.f;
  const float syf = oy * s, sxf = ox * s;
  const int y0 = (int)syf, x0 = (int)sxf;
  const int y1 = imin(y0 + 1, 15), x1 = imin(x0 + 1, 15);
  const float wy = syf - (float)y0, wx = sxf - (float)x0;
  const float r0 = p[y0 * 16 + x0] * (1.f - wx) + p[y0 * 16 + x1] * wx;
  const float r1 = p[y1 * 16 + x0] * (1.f - wx) + p[y1 * 16 + x1] * wx;
  return r0 * (1.f - wy) + r1 * wy;
}

__global__ __launch_bounds__(256) void k_resize(const float* __restrict__ kv16,
    short* __restrict__ Kp, short* __restrict__ Vp) {
  const int idx = blockIdx.x * 256 + threadIdx.x;
  {
    const int pos = idx & 31;
    int rest = idx >> 5;
    const int key = rest & 1023; rest >>= 10;
    const int h = rest & 3; const int b = rest >> 2;
    const int ch = h * 32 + sigma(pos);
    Kp[idx] = f2bf(bilin16(kv16 + (b * 256 + ch) * 256, key));
  }
  {
    const int keypos = idx & 1023;
    int rest = idx >> 10;
    const int d = rest & 31; rest >>= 5;
    const int h = rest & 3; const int b = rest >> 2;
    const int key = (keypos & ~31) | sigma(keypos & 31);
    const int ch = 128 + h * 32 + d;
    Vp[idx] = f2bf(bilin16(kv16 + (b * 256 + ch) * 256, key));
  }
}

// ---------------------------------------------------------------------------
// K4: FUSED Q-GEMM -> attention -> w_out GEMM, KEY-SPLIT x2.
// grid (128 q-tiles of 32, 8 b) = 1024 blocks, 512 thr = 8 waves.
// wave w8 = (ks, h): head h, keys [ks*512, ks*512+512). Unnormalized
// (oacc, ls) are additive across key-halves (no max-subtraction), merged
// via phase-reused LDS pool: QT -> Op/Ls(f32) -> AT. 32 waves/CU target.
// ---------------------------------------------------------------------------
__global__ __launch_bounds__(512, 8) void k_attn(const short* __restrict__ dwQ,
    const float* __restrict__ pw_q, const short* __restrict__ Kp,
    const short* __restrict__ Vp, const float* __restrict__ w_out,
    float* __restrict__ out) {
  const int b = blockIdx.y;
  const int q0 = blockIdx.x * 32;
  const int t = threadIdx.x, w8 = t >> 6, l = t & 63;
  const int h = w8 & 3, ks = w8 >> 2;
  const int lr = l & 15, lg = l >> 4;
  // LDS pool, phase-reused:
  //   phase A: QT short [32][136]            (8704 B)  @0
  //   phase B: Op float [8][32][32] (32768)  @0 ; Ls float [8][32] @32768
  //   phase C: AT short [32][136]            (8704 B)  @0
  __shared__ __align__(16) char POOL[33792];
  short* QT = (short*)POOL;
  float* Op = (float*)POOL;
  float* Ls = (float*)(POOL + 32768);
  short* AT = (short*)POOL;

  // ---- phase A: stage dwQ tile (512 thr x one 16B load) ----
  {
    const int q = t >> 4, c16 = t & 15;
    bf16x8 v = *reinterpret_cast<const bf16x8*>(dwQ + (b * 4096 + q0 + q) * 128 + c16 * 8);
    *reinterpret_cast<bf16x8*>(&QT[q * 136 + c16 * 8]) = v;
  }
  __syncthreads();

  // ---- Q-gen (duplicated across ks halves; same result, parallel) ----
  bf16x8 qf[2];
  {
    f32x4 aq[2][2];  // [ot][qt]
    #pragma unroll
    for (int ot = 0; ot < 2; ++ot)
      #pragma unroll
      for (int qt = 0; qt < 2; ++qt) aq[ot][qt] = f32x4{0.f, 0.f, 0.f, 0.f};
    #pragma unroll
    for (int kk = 0; kk < 4; ++kk) {
      const int c0 = kk * 32 + lg * 8;
      bf16x8 bfr[2];
      #pragma unroll
      for (int qt = 0; qt < 2; ++qt)
        bfr[qt] = *reinterpret_cast<const bf16x8*>(&QT[(qt * 16 + lr) * 136 + c0]);
      #pragma unroll
      for (int ot = 0; ot < 2; ++ot) {
        bf16x8 afr = cvt8(pw_q + ((h * 2 + ot) * 16 + lr) * 128 + c0);
        #pragma unroll
        for (int qt = 0; qt < 2; ++qt)
          aq[ot][qt] = __builtin_amdgcn_mfma_f32_16x16x32_bf16(afr, bfr[qt], aq[ot][qt], 0, 0, 0);
      }
    }
    const float qs = 0.25505403f;  // 1/sqrt(32)/ln(2)
    #pragma unroll
    for (int qt = 0; qt < 2; ++qt) {
      u32x4 qw;
      qw[0] = pkbf(aq[0][qt][0] * qs, aq[0][qt][1] * qs);
      qw[1] = pkbf(aq[0][qt][2] * qs, aq[0][qt][3] * qs);
      qw[2] = pkbf(aq[1][qt][0] * qs, aq[1][qt][1] * qs);
      qw[3] = pkbf(aq[1][qt][2] * qs, aq[1][qt][3] * qs);
      qf[qt] = *reinterpret_cast<bf16x8*>(&qw);
    }
  }
  __syncthreads();  // QT dead; Op region may be written after this

  // ---- main loop: this wave's 512-key half (16 iters) ----
  const short* Kb = Kp + (b * 4 + h) * 32768;
  const short* Vb = Vp + (b * 4 + h) * 32768;
  f32x4 oacc[2][2];
  float ls[2];
  #pragma unroll
  for (int qt = 0; qt < 2; ++qt) {
    oacc[qt][0] = f32x4{0.f, 0.f, 0.f, 0.f};
    oacc[qt][1] = f32x4{0.f, 0.f, 0.f, 0.f};
    ls[qt] = 0.f;
  }
  const int kend = ks * 512 + 512;
  for (int kc = ks * 512; kc < kend; kc += 32) {
    bf16x8 kf[2], vf[2];
    #pragma unroll
    for (int tt = 0; tt < 2; ++tt) {
      kf[tt] = *reinterpret_cast<const bf16x8*>(Kb + (kc + tt * 16 + lr) * 32 + lg * 8);
      vf[tt] = *reinterpret_cast<const bf16x8*>(Vb + (tt * 16 + lr) * 1024 + kc + lg * 8);
    }
    #pragma unroll
    for (int qt = 0; qt < 2; ++qt) {
      const f32x4 z = f32x4{0.f, 0.f, 0.f, 0.f};
      f32x4 s0 = __builtin_amdgcn_mfma_f32_16x16x32_bf16(kf[0], qf[qt], z, 0, 0, 0);
      f32x4 s1 = __builtin_amdgcn_mfma_f32_16x16x32_bf16(kf[1], qf[qt], z, 0, 0, 0);
      float p0[4], p1[4];
      #pragma unroll
      for (int r = 0; r < 4; ++r) {
        p0[r] = __builtin_amdgcn_exp2f(s0[r]);
        p1[r] = __builtin_amdgcn_exp2f(s1[r]);
      }
      ls[qt] += ((p0[0] + p0[1]) + (p0[2] + p0[3])) + ((p1[0] + p1[1]) + (p1[2] + p1[3]));
      u32x4 pw;
      pw[0] = pkbf(p0[0], p0[1]);
      pw[1] = pkbf(p0[2], p0[3]);
      pw[2] = pkbf(p1[0], p1[1]);
      pw[3] = pkbf(p1[2], p1[3]);
      bf16x8 pf = *reinterpret_cast<bf16x8*>(&pw);
      oacc[qt][0] = __builtin_amdgcn_mfma_f32_16x16x32_bf16(pf, vf[0], oacc[qt][0], 0, 0, 0);
      oacc[qt][1] = __builtin_amdgcn_mfma_f32_16x16x32_bf16(pf, vf[1], oacc[qt][1], 0, 0, 0);
    }
  }

  // ---- phase B: write unnormalized partials ----
  #pragma unroll
  for (int qt = 0; qt < 2; ++qt) {
    float s = ls[qt];
    s += __shfl_xor(s, 16);
    s += __shfl_xor(s, 32);
    if (lg == 0) Ls[w8 * 32 + qt * 16 + lr] = s;  // per-q partial denom
    #pragma unroll
    for (int tt = 0; tt < 2; ++tt)
      #pragma unroll
      for (int r = 0; r < 4; ++r)
        Op[w8 * 1024 + (qt * 16 + lg * 4 + r) * 32 + tt * 16 + lr] = oacc[qt][tt][r];
  }
  __syncthreads();

  // ---- merge halves + normalize; result held in regs across the barrier ----
  const int mq = l >> 1, md = ks * 16 + (l & 1) * 8;
  bf16x8 atv;
  {
    const f32x4* OpV = (const f32x4*)POOL;
    f32x4 a0 = OpV[(h * 1024 + mq * 32 + md) >> 2];
    f32x4 a1 = OpV[(h * 1024 + mq * 32 + md + 4) >> 2];
    f32x4 b0 = OpV[((4 + h) * 1024 + mq * 32 + md) >> 2];
    f32x4 b1 = OpV[((4 + h) * 1024 + mq * 32 + md + 4) >> 2];
    const float inv = 1.f / (Ls[h * 32 + mq] + Ls[(4 + h) * 32 + mq]);
    f32x4 va = (a0 + b0) * inv;
    f32x4 vb = (a1 + b1) * inv;
    u32x4 pk;
    pk[0] = pkbf(va[0], va[1]); pk[1] = pkbf(va[2], va[3]);
    pk[2] = pkbf(vb[0], vb[1]); pk[3] = pkbf(vb[2], vb[3]);
    atv = *reinterpret_cast<bf16x8*>(&pk);
  }
  __syncthreads();  // all Op/Ls reads done before AT overwrites the pool
  *reinterpret_cast<bf16x8*>(&AT[mq * 136 + h * 32 + md]) = atv;
  __syncthreads();

  // ---- phase C: out GEMM, wave w8 -> j in [w8*16, w8*16+16) ----
  f32x4 ao[2];
  ao[0] = f32x4{0.f, 0.f, 0.f, 0.f};
  ao[1] = f32x4{0.f, 0.f, 0.f, 0.f};
  #pragma unroll
  for (int kk = 0; kk < 4; ++kk) {
    const int c0 = kk * 32 + lg * 8;
    bf16x8 afr = cvt8(w_out + (w8 * 16 + lr) * 128 + c0);
    #pragma unroll
    for (int qt = 0; qt < 2; ++qt) {
      bf16x8 bfr = *reinterpret_cast<const bf16x8*>(&AT[(qt * 16 + lr) * 136 + c0]);
      ao[qt] = __builtin_amdgcn_mfma_f32_16x16x32_bf16(afr, bfr, ao[qt], 0, 0, 0);
    }
  }
  #pragma unroll
  for (int qt = 0; qt < 2; ++qt)
    #pragma unroll
    for (int r = 0; r < 4; ++r) {
      const int j = w8 * 16 + lg * 4 + r;
      out[(b * 128 + j) * 4096 + q0 + qt * 16 + lr] = ao[qt][r];
    }
}

// ---------------------------------------------------------------------------
extern "C" void kernel_launch(void* const* d_in, const int* in_sizes, int n_in,
                              void* d_out, int out_size, void* d_ws, size_t ws_size,
                              hipStream_t stream) {
  const float* x     = (const float*)d_in[0];
  const float* skip  = (const float*)d_in[1];
  const float* dw_q  = (const float*)d_in[2];
  const float* pw_q  = (const float*)d_in[3];
  const float* dw_kv = (const float*)d_in[4];
  const float* pw_kv = (const float*)d_in[5];
  const float* w_out = (const float*)d_in[6];
  float* out = (float*)d_out;
  (void)in_sizes; (void)n_in; (void)out_size; (void)ws_size;

  // workspace: dwQ bf16 [8][4096][128] @0 (8MB); kv16 f32 @8MB (2MB);
  //            Kp bf16 @10MB (2MB); Vp bf16 @12MB (2MB)
  char* wsb = (char*)d_ws;
  short* dwQ  = (short*)(wsb);
  float* kv16 = (float*)(wsb + (size_t)(8u << 20));
  short* Kp   = (short*)(wsb + (size_t)(10u << 20));
  short* Vp   = (short*)(wsb + (size_t)(12u << 20));

  k_dwq<<<dim3(64, 4, 8), dim3(256), 0, stream>>>(skip, dw_q, dwQ);
  k_kvgen<<<dim3(16, 2, 8), dim3(512), 0, stream>>>(x, dw_kv, pw_kv, kv16);
  k_resize<<<dim3(4096), dim3(256), 0, stream>>>(kv16, Kp, Vp);
  k_attn<<<dim3(128, 8), dim3(512), 0, stream>>>(dwQ, pw_q, Kp, Vp, w_out, out);
}

// Round 10
// 244.537 us; speedup vs baseline: 1.1127x; 1.1127x over previous
//
#include <hip/hip_runtime.h>
#include <hip/hip_bf16.h>

typedef __attribute__((ext_vector_type(4))) float f32x4;
typedef __attribute__((ext_vector_type(8))) short bf16x8;
typedef __attribute__((ext_vector_type(4))) unsigned u32x4;

#define DEV static __device__ __forceinline__

DEV int imin(int a, int b) { return a < b ? a : b; }

DEV short f2bf(float f) {
  union { float f; unsigned u; } v; v.f = f;
  unsigned r = (v.u + 0x7fffu + ((v.u >> 16) & 1u)) >> 16;
  return (short)r;
}

DEV unsigned pkbf(float lo, float hi) {
  unsigned r;
  asm("v_cvt_pk_bf16_f32 %0, %1, %2" : "=v"(r) : "v"(lo), "v"(hi));
  return r;
}

DEV bf16x8 cvt8(const float* __restrict__ p) {
  f32x4 a = *reinterpret_cast<const f32x4*>(p);
  f32x4 b = *reinterpret_cast<const f32x4*>(p + 4);
  bf16x8 r;
  r[0] = f2bf(a[0]); r[1] = f2bf(a[1]); r[2] = f2bf(a[2]); r[3] = f2bf(a[3]);
  r[4] = f2bf(b[0]); r[5] = f2bf(b[1]); r[6] = f2bf(b[2]); r[7] = f2bf(b[3]);
  return r;
}

// kslot->element permutation shared by {P,V} (keys) and {Q,K} (d):
// sigma(s) = ((s&4)<<2) | ((s>>3)<<2) | (s&3)
DEV int sigma(int s) { return ((s & 4) << 2) | ((s >> 3) << 2) | (s & 3); }

// ---------------------------------------------------------------------------
// K1: depthwise 3x3 on skip -> dwQ bf16 [b][pix(4096)][c(128)]
// grid (64 y, 4 c-quarters, 8 b) = 2048 blocks, 256 thr.
// ---------------------------------------------------------------------------
__global__ __launch_bounds__(256) void k_dwq(const float* __restrict__ skip,
    const float* __restrict__ dw_q, short* __restrict__ dwQ) {
  const int b = blockIdx.z, cq = blockIdx.y, y = blockIdx.x;
  __shared__ __align__(16) short T[64][40];  // [x][32 c], pad 8
  const int t = threadIdx.x;
  {
    const int x = t & 63, cg = t >> 6;
    #pragma unroll
    for (int i = 0; i < 8; ++i) {
      const int cl = cg * 8 + i;
      const int c = cq * 32 + cl;
      const float* sp = skip + (b * 128 + c) * 4096;
      const float* wp = dw_q + c * 9;
      float acc = 0.f;
      #pragma unroll
      for (int ky = 0; ky < 3; ++ky) {
        const int yy = y + ky - 1;
        if (yy < 0 || yy > 63) continue;
        #pragma unroll
        for (int kx = 0; kx < 3; ++kx) {
          const int xx = x + kx - 1;
          if (xx < 0 || xx > 63) continue;
          acc += sp[yy * 64 + xx] * wp[ky * 3 + kx];
        }
      }
      T[x][cl] = f2bf(acc);
    }
  }
  __syncthreads();
  const int x2 = t >> 2, cc = t & 3;
  bf16x8 v = *reinterpret_cast<const bf16x8*>(&T[x2][cc * 8]);
  *reinterpret_cast<bf16x8*>(dwQ + (b * 4096 + y * 64 + x2) * 128 + cq * 32 + cc * 8) = v;
}

// ---------------------------------------------------------------------------
// K2: kv16 = pw_kv( dw3x3(x) )  f32 [b][o(256)][pix(256)]
// grid (16 rows, 2 o-halves, 8 b) = 256 blocks, 512 thr (8 waves x 16 o).
// ---------------------------------------------------------------------------
__global__ __launch_bounds__(512) void k_kvgen(const float* __restrict__ x,
    const float* __restrict__ dw_kv, const float* __restrict__ pw_kv,
    float* __restrict__ kv16) {
  const int b = blockIdx.z;
  const int oh = blockIdx.y;
  const int pq = blockIdx.x;  // image row (16 pixels)
  __shared__ __align__(16) short dwxT[16][264];
  const int t = threadIdx.x;
  {
    const int pl = t & 15;
    const int cg = t >> 4;  // 32 groups of 8 channels
    const int py = pq, px = pl;
    #pragma unroll
    for (int i = 0; i < 8; ++i) {
      const int c = cg * 8 + i;
      const float* sp = x + (b * 256 + c) * 256;
      const float* wp = dw_kv + c * 9;
      float acc = 0.f;
      #pragma unroll
      for (int ky = 0; ky < 3; ++ky) {
        const int yy = py + ky - 1;
        if (yy < 0 || yy > 15) continue;
        #pragma unroll
        for (int kx = 0; kx < 3; ++kx) {
          const int xx = px + kx - 1;
          if (xx < 0 || xx > 15) continue;
          acc += sp[yy * 16 + xx] * wp[ky * 3 + kx];
        }
      }
      dwxT[pl][c] = f2bf(acc);
    }
  }
  __syncthreads();
  const int w = t >> 6, l = t & 63, lr = l & 15, lg = l >> 4;
  f32x4 acc = f32x4{0.f, 0.f, 0.f, 0.f};
  const int o = oh * 128 + w * 16 + lr;  // A-row for this lane
  #pragma unroll
  for (int kk = 0; kk < 8; ++kk) {
    const int c0 = kk * 32 + lg * 8;
    bf16x8 bfr = *reinterpret_cast<const bf16x8*>(&dwxT[lr][c0]);
    bf16x8 afr = cvt8(pw_kv + o * 256 + c0);
    acc = __builtin_amdgcn_mfma_f32_16x16x32_bf16(afr, bfr, acc, 0, 0, 0);
  }
  #pragma unroll
  for (int r = 0; r < 4; ++r) {
    const int oo = oh * 128 + w * 16 + lg * 4 + r;
    kv16[(b * 256 + oo) * 256 + pq * 16 + lr] = acc[r];
  }
}

// ---------------------------------------------------------------------------
// K3: bilinear resize 16x16 -> 32x32 (align_corners), split k/v, with the
// sigma permutation baked in:
//   Kp bf16 [bh][key(1024)][pos(32)]  where pos holds d = sigma(pos)
//   Vp bf16 [bh][d(32)][kb(32)][pos(32)] where pos holds key kb*32+sigma(pos)
// ---------------------------------------------------------------------------
DEV float bilin16(const float* __restrict__ p, int key) {
  const int oy = key >> 5, ox = key & 31;
  const float s = 15.f / 31.f;
  const float syf = oy * s, sxf = ox * s;
  const int y0 = (int)syf, x0 = (int)sxf;
  const int y1 = imin(y0 + 1, 15), x1 = imin(x0 + 1, 15);
  const float wy = syf - (float)y0, wx = sxf - (float)x0;
  const float r0 = p[y0 * 16 + x0] * (1.f - wx) + p[y0 * 16 + x1] * wx;
  const float r1 = p[y1 * 16 + x0] * (1.f - wx) + p[y1 * 16 + x1] * wx;
  return r0 * (1.f - wy) + r1 * wy;
}

__global__ __launch_bounds__(256) void k_resize(const float* __restrict__ kv16,
    short* __restrict__ Kp, short* __restrict__ Vp) {
  const int idx = blockIdx.x * 256 + threadIdx.x;
  {
    const int pos = idx & 31;
    int rest = idx >> 5;
    const int key = rest & 1023; rest >>= 10;
    const int h = rest & 3; const int b = rest >> 2;
    const int ch = h * 32 + sigma(pos);
    Kp[idx] = f2bf(bilin16(kv16 + (b * 256 + ch) * 256, key));
  }
  {
    const int keypos = idx & 1023;
    int rest = idx >> 10;
    const int d = rest & 31; rest >>= 5;
    const int h = rest & 3; const int b = rest >> 2;
    const int key = (keypos & ~31) | sigma(keypos & 31);
    const int ch = 128 + h * 32 + d;
    Vp[idx] = f2bf(bilin16(kv16 + (b * 256 + ch) * 256, key));
  }
}

// ---------------------------------------------------------------------------
// K4: FUSED Q-GEMM -> attention -> w_out GEMM, 16-QUERY TILES.
// grid (256 q-tiles of 16, 8 b) = 2048 blocks = 8 blocks/CU, 256 thr
// (4 waves; wave = head) -> 32 waves/CU at ~40-48 VGPR (no spill, unlike
// the R8 key-split whose 64-VGPR clamp spilled 400 MB to scratch).
// Register-resident softmax->PV via sigma-permuted Kp/Vp.
// ---------------------------------------------------------------------------
__global__ __launch_bounds__(256, 8) void k_attn(const short* __restrict__ dwQ,
    const float* __restrict__ pw_q, const short* __restrict__ Kp,
    const short* __restrict__ Vp, const float* __restrict__ w_out,
    float* __restrict__ out) {
  const int b = blockIdx.y;
  const int q0 = blockIdx.x * 16;
  const int t = threadIdx.x, h = t >> 6, l = t & 63;
  const int lr = l & 15, lg = l >> 4;
  __shared__ __align__(16) short QT[16][136];   // dwQ tile [q][c]
  __shared__ __align__(16) short AT[16][136];   // att tile [q][o]

  // ---- stage dwQ rows q0..q0+15 (one 16B load per thread) ----
  {
    const int q = t >> 4, c16 = t & 15;
    bf16x8 v = *reinterpret_cast<const bf16x8*>(dwQ + (b * 4096 + q0 + q) * 128 + c16 * 8);
    *reinterpret_cast<bf16x8*>(&QT[q][c16 * 8]) = v;
  }
  __syncthreads();

  // ---- Q-gen: wave h computes Q[16q][32d]; stays in registers as the
  //      QK^T B-fragment (d-order = sigma, matching Kp) ----
  bf16x8 qf;
  {
    f32x4 aq[2];
    aq[0] = f32x4{0.f, 0.f, 0.f, 0.f};
    aq[1] = f32x4{0.f, 0.f, 0.f, 0.f};
    #pragma unroll
    for (int kk = 0; kk < 4; ++kk) {
      const int c0 = kk * 32 + lg * 8;
      bf16x8 bfr = *reinterpret_cast<const bf16x8*>(&QT[lr][c0]);
      #pragma unroll
      for (int ot = 0; ot < 2; ++ot) {
        bf16x8 afr = cvt8(pw_q + ((h * 2 + ot) * 16 + lr) * 128 + c0);
        aq[ot] = __builtin_amdgcn_mfma_f32_16x16x32_bf16(afr, bfr, aq[ot], 0, 0, 0);
      }
    }
    const float qs = 0.25505403f;  // 1/sqrt(32)/ln(2), exp2 later
    u32x4 qw;
    qw[0] = pkbf(aq[0][0] * qs, aq[0][1] * qs);
    qw[1] = pkbf(aq[0][2] * qs, aq[0][3] * qs);
    qw[2] = pkbf(aq[1][0] * qs, aq[1][1] * qs);
    qw[3] = pkbf(aq[1][2] * qs, aq[1][3] * qs);
    qf = *reinterpret_cast<bf16x8*>(&qw);
  }

  // ---- attention main loop (pure register dataflow, 32 iters) ----
  const short* Kb = Kp + (b * 4 + h) * 32768;
  const short* Vb = Vp + (b * 4 + h) * 32768;
  f32x4 oacc[2];
  oacc[0] = f32x4{0.f, 0.f, 0.f, 0.f};
  oacc[1] = f32x4{0.f, 0.f, 0.f, 0.f};
  float ls = 0.f;
  for (int kc = 0; kc < 1024; kc += 32) {
    bf16x8 kf[2], vf[2];
    #pragma unroll
    for (int tt = 0; tt < 2; ++tt) {
      kf[tt] = *reinterpret_cast<const bf16x8*>(Kb + (kc + tt * 16 + lr) * 32 + lg * 8);
      vf[tt] = *reinterpret_cast<const bf16x8*>(Vb + (tt * 16 + lr) * 1024 + kc + lg * 8);
    }
    const f32x4 z = f32x4{0.f, 0.f, 0.f, 0.f};
    // S^T: lane holds q = lr; keys lg*4+r (s0), 16+lg*4+r (s1)
    f32x4 s0 = __builtin_amdgcn_mfma_f32_16x16x32_bf16(kf[0], qf, z, 0, 0, 0);
    f32x4 s1 = __builtin_amdgcn_mfma_f32_16x16x32_bf16(kf[1], qf, z, 0, 0, 0);
    float p0[4], p1[4];
    #pragma unroll
    for (int r = 0; r < 4; ++r) {
      p0[r] = __builtin_amdgcn_exp2f(s0[r]);
      p1[r] = __builtin_amdgcn_exp2f(s1[r]);
    }
    ls += ((p0[0] + p0[1]) + (p0[2] + p0[3])) + ((p1[0] + p1[1]) + (p1[2] + p1[3]));
    // PV A-frag direct: kslot order matches sigma-permuted Vp
    u32x4 pw;
    pw[0] = pkbf(p0[0], p0[1]);
    pw[1] = pkbf(p0[2], p0[3]);
    pw[2] = pkbf(p1[0], p1[1]);
    pw[3] = pkbf(p1[2], p1[3]);
    bf16x8 pf = *reinterpret_cast<bf16x8*>(&pw);
    oacc[0] = __builtin_amdgcn_mfma_f32_16x16x32_bf16(pf, vf[0], oacc[0], 0, 0, 0);
    oacc[1] = __builtin_amdgcn_mfma_f32_16x16x32_bf16(pf, vf[1], oacc[1], 0, 0, 0);
  }

  // ---- normalize + att tile to LDS ----
  {
    float s = ls;
    s += __shfl_xor(s, 16);
    s += __shfl_xor(s, 32);
    const float inv = 1.f / s;  // valid for q = lr
    #pragma unroll
    for (int r = 0; r < 4; ++r) {
      const float invr = __shfl(inv, lg * 4 + r);
      const int q = lg * 4 + r;
      #pragma unroll
      for (int tt = 0; tt < 2; ++tt)
        AT[q][h * 32 + tt * 16 + lr] = f2bf(oacc[tt][r] * invr);
    }
  }
  __syncthreads();

  // ---- out GEMM: wave h -> j in [h*32, h*32+32) ----
  f32x4 ao[2];
  ao[0] = f32x4{0.f, 0.f, 0.f, 0.f};
  ao[1] = f32x4{0.f, 0.f, 0.f, 0.f};
  #pragma unroll
  for (int kk = 0; kk < 4; ++kk) {
    const int c0 = kk * 32 + lg * 8;
    bf16x8 bfr = *reinterpret_cast<const bf16x8*>(&AT[lr][c0]);
    #pragma unroll
    for (int jt = 0; jt < 2; ++jt) {
      bf16x8 afr = cvt8(w_out + ((h * 2 + jt) * 16 + lr) * 128 + c0);
      ao[jt] = __builtin_amdgcn_mfma_f32_16x16x32_bf16(afr, bfr, ao[jt], 0, 0, 0);
    }
  }
  #pragma unroll
  for (int jt = 0; jt < 2; ++jt)
    #pragma unroll
    for (int r = 0; r < 4; ++r) {
      const int j = (h * 2 + jt) * 16 + lg * 4 + r;
      out[(b * 128 + j) * 4096 + q0 + lr] = ao[jt][r];
    }
}

// ---------------------------------------------------------------------------
extern "C" void kernel_launch(void* const* d_in, const int* in_sizes, int n_in,
                              void* d_out, int out_size, void* d_ws, size_t ws_size,
                              hipStream_t stream) {
  const float* x     = (const float*)d_in[0];
  const float* skip  = (const float*)d_in[1];
  const float* dw_q  = (const float*)d_in[2];
  const float* pw_q  = (const float*)d_in[3];
  const float* dw_kv = (const float*)d_in[4];
  const float* pw_kv = (const float*)d_in[5];
  const float* w_out = (const float*)d_in[6];
  float* out = (float*)d_out;
  (void)in_sizes; (void)n_in; (void)out_size; (void)ws_size;

  // workspace: dwQ bf16 [8][4096][128] @0 (8MB); kv16 f32 @8MB (2MB);
  //            Kp bf16 @10MB (2MB); Vp bf16 @12MB (2MB)
  char* wsb = (char*)d_ws;
  short* dwQ  = (short*)(wsb);
  float* kv16 = (float*)(wsb + (size_t)(8u << 20));
  short* Kp   = (short*)(wsb + (size_t)(10u << 20));
  short* Vp   = (short*)(wsb + (size_t)(12u << 20));

  k_dwq<<<dim3(64, 4, 8), dim3(256), 0, stream>>>(skip, dw_q, dwQ);
  k_kvgen<<<dim3(16, 2, 8), dim3(512), 0, stream>>>(x, dw_kv, pw_kv, kv16);
  k_resize<<<dim3(4096), dim3(256), 0, stream>>>(kv16, Kp, Vp);
  k_attn<<<dim3(256, 8), dim3(256), 0, stream>>>(dwQ, pw_q, Kp, Vp, w_out, out);
}

// Round 12
// 243.834 us; speedup vs baseline: 1.1160x; 1.0029x over previous
//
#include <hip/hip_runtime.h>
#include <hip/hip_bf16.h>

typedef __attribute__((ext_vector_type(4))) float f32x4;
typedef __attribute__((ext_vector_type(8))) short bf16x8;
typedef __attribute__((ext_vector_type(4))) unsigned u32x4;

#define DEV static __device__ __forceinline__

DEV int imin(int a, int b) { return a < b ? a : b; }

DEV short f2bf(float f) {
  union { float f; unsigned u; } v; v.f = f;
  unsigned r = (v.u + 0x7fffu + ((v.u >> 16) & 1u)) >> 16;
  return (short)r;
}

DEV unsigned pkbf(float lo, float hi) {
  unsigned r;
  asm("v_cvt_pk_bf16_f32 %0, %1, %2" : "=v"(r) : "v"(lo), "v"(hi));
  return r;
}

DEV bf16x8 cvt8(const float* __restrict__ p) {
  f32x4 a = *reinterpret_cast<const f32x4*>(p);
  f32x4 b = *reinterpret_cast<const f32x4*>(p + 4);
  bf16x8 r;
  r[0] = f2bf(a[0]); r[1] = f2bf(a[1]); r[2] = f2bf(a[2]); r[3] = f2bf(a[3]);
  r[4] = f2bf(b[0]); r[5] = f2bf(b[1]); r[6] = f2bf(b[2]); r[7] = f2bf(b[3]);
  return r;
}

// kslot->element permutation shared by {P,V} (keys) and {Q,K} (d):
// sigma(s) = ((s&4)<<2) | ((s>>3)<<2) | (s&3)
DEV int sigma(int s) { return ((s & 4) << 2) | ((s >> 3) << 2) | (s & 3); }

// ---------------------------------------------------------------------------
// K1: depthwise 3x3 on skip -> dwQ bf16 [b][pix(4096)][c(128)]
// grid (64 y, 4 c-quarters, 8 b) = 2048 blocks, 256 thr.
// ---------------------------------------------------------------------------
__global__ __launch_bounds__(256) void k_dwq(const float* __restrict__ skip,
    const float* __restrict__ dw_q, short* __restrict__ dwQ) {
  const int b = blockIdx.z, cq = blockIdx.y, y = blockIdx.x;
  __shared__ __align__(16) short T[64][40];  // [x][32 c], pad 8
  const int t = threadIdx.x;
  {
    const int x = t & 63, cg = t >> 6;
    #pragma unroll
    for (int i = 0; i < 8; ++i) {
      const int cl = cg * 8 + i;
      const int c = cq * 32 + cl;
      const float* sp = skip + (b * 128 + c) * 4096;
      const float* wp = dw_q + c * 9;
      float acc = 0.f;
      #pragma unroll
      for (int ky = 0; ky < 3; ++ky) {
        const int yy = y + ky - 1;
        if (yy < 0 || yy > 63) continue;
        #pragma unroll
        for (int kx = 0; kx < 3; ++kx) {
          const int xx = x + kx - 1;
          if (xx < 0 || xx > 63) continue;
          acc += sp[yy * 64 + xx] * wp[ky * 3 + kx];
        }
      }
      T[x][cl] = f2bf(acc);
    }
  }
  __syncthreads();
  const int x2 = t >> 2, cc = t & 3;
  bf16x8 v = *reinterpret_cast<const bf16x8*>(&T[x2][cc * 8]);
  *reinterpret_cast<bf16x8*>(dwQ + (b * 4096 + y * 64 + x2) * 128 + cq * 32 + cc * 8) = v;
}

// ---------------------------------------------------------------------------
// K2: kv16 = pw_kv( dw3x3(x) )  f32 [b][o(256)][pix(256)]
// grid (16 rows, 2 o-halves, 8 b) = 256 blocks, 512 thr (8 waves x 16 o).
// ---------------------------------------------------------------------------
__global__ __launch_bounds__(512) void k_kvgen(const float* __restrict__ x,
    const float* __restrict__ dw_kv, const float* __restrict__ pw_kv,
    float* __restrict__ kv16) {
  const int b = blockIdx.z;
  const int oh = blockIdx.y;
  const int pq = blockIdx.x;  // image row (16 pixels)
  __shared__ __align__(16) short dwxT[16][264];
  const int t = threadIdx.x;
  {
    const int pl = t & 15;
    const int cg = t >> 4;  // 32 groups of 8 channels
    const int py = pq, px = pl;
    #pragma unroll
    for (int i = 0; i < 8; ++i) {
      const int c = cg * 8 + i;
      const float* sp = x + (b * 256 + c) * 256;
      const float* wp = dw_kv + c * 9;
      float acc = 0.f;
      #pragma unroll
      for (int ky = 0; ky < 3; ++ky) {
        const int yy = py + ky - 1;
        if (yy < 0 || yy > 15) continue;
        #pragma unroll
        for (int kx = 0; kx < 3; ++kx) {
          const int xx = px + kx - 1;
          if (xx < 0 || xx > 15) continue;
          acc += sp[yy * 16 + xx] * wp[ky * 3 + kx];
        }
      }
      dwxT[pl][c] = f2bf(acc);
    }
  }
  __syncthreads();
  const int w = t >> 6, l = t & 63, lr = l & 15, lg = l >> 4;
  f32x4 acc = f32x4{0.f, 0.f, 0.f, 0.f};
  const int o = oh * 128 + w * 16 + lr;  // A-row for this lane
  #pragma unroll
  for (int kk = 0; kk < 8; ++kk) {
    const int c0 = kk * 32 + lg * 8;
    bf16x8 bfr = *reinterpret_cast<const bf16x8*>(&dwxT[lr][c0]);
    bf16x8 afr = cvt8(pw_kv + o * 256 + c0);
    acc = __builtin_amdgcn_mfma_f32_16x16x32_bf16(afr, bfr, acc, 0, 0, 0);
  }
  #pragma unroll
  for (int r = 0; r < 4; ++r) {
    const int oo = oh * 128 + w * 16 + lg * 4 + r;
    kv16[(b * 256 + oo) * 256 + pq * 16 + lr] = acc[r];
  }
}

// ---------------------------------------------------------------------------
// K3: bilinear resize 16x16 -> 32x32 (align_corners), split k/v, with the
// sigma permutation baked in:
//   Kp bf16 [bh][key(1024)][pos(32)]  where pos holds d = sigma(pos)
//   Vp bf16 [bh][d(32)][kb(32)][pos(32)] where pos holds key kb*32+sigma(pos)
// ---------------------------------------------------------------------------
DEV float bilin16(const float* __restrict__ p, int key) {
  const int oy = key >> 5, ox = key & 31;
  const float s = 15.f / 31.f;
  const float syf = oy * s, sxf = ox * s;
  const int y0 = (int)syf, x0 = (int)sxf;
  const int y1 = imin(y0 + 1, 15), x1 = imin(x0 + 1, 15);
  const float wy = syf - (float)y0, wx = sxf - (float)x0;
  const float r0 = p[y0 * 16 + x0] * (1.f - wx) + p[y0 * 16 + x1] * wx;
  const float r1 = p[y1 * 16 + x0] * (1.f - wx) + p[y1 * 16 + x1] * wx;
  return r0 * (1.f - wy) + r1 * wy;
}

__global__ __launch_bounds__(256) void k_resize(const float* __restrict__ kv16,
    short* __restrict__ Kp, short* __restrict__ Vp) {
  const int idx = blockIdx.x * 256 + threadIdx.x;
  {
    const int pos = idx & 31;
    int rest = idx >> 5;
    const int key = rest & 1023; rest >>= 10;
    const int h = rest & 3; const int b = rest >> 2;
    const int ch = h * 32 + sigma(pos);
    Kp[idx] = f2bf(bilin16(kv16 + (b * 256 + ch) * 256, key));
  }
  {
    const int keypos = idx & 1023;
    int rest = idx >> 10;
    const int d = rest & 31; rest >>= 5;
    const int h = rest & 3; const int b = rest >> 2;
    const int key = (keypos & ~31) | sigma(keypos & 31);
    const int ch = 128 + h * 32 + d;
    Vp[idx] = f2bf(bilin16(kv16 + (b * 256 + ch) * 256, key));
  }
}

// ---------------------------------------------------------------------------
// K4: FUSED Q-GEMM -> attention -> w_out GEMM, 16-QUERY TILES.
// grid (256 q-tiles of 16, 8 b) = 2048 blocks, 256 thr (4 waves; wave=head)
// = 8192 waves = 100% of wave slots. NO min-waves launch bound: R8/R10
// proved the ,8 clamp forces VGPR=32 + scratch spill (the 126/157 us
// regressions). Natural ~40 VGPR <= 64 still admits 8 waves/SIMD.
// Register-resident softmax->PV via sigma-permuted Kp/Vp.
// ---------------------------------------------------------------------------
__global__ __launch_bounds__(256) void k_attn(const short* __restrict__ dwQ,
    const float* __restrict__ pw_q, const short* __restrict__ Kp,
    const short* __restrict__ Vp, const float* __restrict__ w_out,
    float* __restrict__ out) {
  const int b = blockIdx.y;
  const int q0 = blockIdx.x * 16;
  const int t = threadIdx.x, h = t >> 6, l = t & 63;
  const int lr = l & 15, lg = l >> 4;
  __shared__ __align__(16) short QT[16][136];   // dwQ tile [q][c]
  __shared__ __align__(16) short AT[16][136];   // att tile [q][o]

  // ---- stage dwQ rows q0..q0+15 (one 16B load per thread) ----
  {
    const int q = t >> 4, c16 = t & 15;
    bf16x8 v = *reinterpret_cast<const bf16x8*>(dwQ + (b * 4096 + q0 + q) * 128 + c16 * 8);
    *reinterpret_cast<bf16x8*>(&QT[q][c16 * 8]) = v;
  }
  __syncthreads();

  // ---- Q-gen: wave h computes Q[16q][32d]; stays in registers as the
  //      QK^T B-fragment (d-order = sigma, matching Kp) ----
  bf16x8 qf;
  {
    f32x4 aq[2];
    aq[0] = f32x4{0.f, 0.f, 0.f, 0.f};
    aq[1] = f32x4{0.f, 0.f, 0.f, 0.f};
    #pragma unroll
    for (int kk = 0; kk < 4; ++kk) {
      const int c0 = kk * 32 + lg * 8;
      bf16x8 bfr = *reinterpret_cast<const bf16x8*>(&QT[lr][c0]);
      #pragma unroll
      for (int ot = 0; ot < 2; ++ot) {
        bf16x8 afr = cvt8(pw_q + ((h * 2 + ot) * 16 + lr) * 128 + c0);
        aq[ot] = __builtin_amdgcn_mfma_f32_16x16x32_bf16(afr, bfr, aq[ot], 0, 0, 0);
      }
    }
    const float qs = 0.25505403f;  // 1/sqrt(32)/ln(2), exp2 later
    u32x4 qw;
    qw[0] = pkbf(aq[0][0] * qs, aq[0][1] * qs);
    qw[1] = pkbf(aq[0][2] * qs, aq[0][3] * qs);
    qw[2] = pkbf(aq[1][0] * qs, aq[1][1] * qs);
    qw[3] = pkbf(aq[1][2] * qs, aq[1][3] * qs);
    qf = *reinterpret_cast<bf16x8*>(&qw);
  }

  // ---- attention main loop (pure register dataflow, 32 iters) ----
  const short* Kb = Kp + (b * 4 + h) * 32768;
  const short* Vb = Vp + (b * 4 + h) * 32768;
  f32x4 oacc[2];
  oacc[0] = f32x4{0.f, 0.f, 0.f, 0.f};
  oacc[1] = f32x4{0.f, 0.f, 0.f, 0.f};
  float ls = 0.f;
  for (int kc = 0; kc < 1024; kc += 32) {
    bf16x8 kf[2], vf[2];
    #pragma unroll
    for (int tt = 0; tt < 2; ++tt) {
      kf[tt] = *reinterpret_cast<const bf16x8*>(Kb + (kc + tt * 16 + lr) * 32 + lg * 8);
      vf[tt] = *reinterpret_cast<const bf16x8*>(Vb + (tt * 16 + lr) * 1024 + kc + lg * 8);
    }
    const f32x4 z = f32x4{0.f, 0.f, 0.f, 0.f};
    // S^T: lane holds q = lr; keys lg*4+r (s0), 16+lg*4+r (s1)
    f32x4 s0 = __builtin_amdgcn_mfma_f32_16x16x32_bf16(kf[0], qf, z, 0, 0, 0);
    f32x4 s1 = __builtin_amdgcn_mfma_f32_16x16x32_bf16(kf[1], qf, z, 0, 0, 0);
    float p0[4], p1[4];
    #pragma unroll
    for (int r = 0; r < 4; ++r) {
      p0[r] = __builtin_amdgcn_exp2f(s0[r]);
      p1[r] = __builtin_amdgcn_exp2f(s1[r]);
    }
    ls += ((p0[0] + p0[1]) + (p0[2] + p0[3])) + ((p1[0] + p1[1]) + (p1[2] + p1[3]));
    // PV A-frag direct: kslot order matches sigma-permuted Vp
    u32x4 pw;
    pw[0] = pkbf(p0[0], p0[1]);
    pw[1] = pkbf(p0[2], p0[3]);
    pw[2] = pkbf(p1[0], p1[1]);
    pw[3] = pkbf(p1[2], p1[3]);
    bf16x8 pf = *reinterpret_cast<bf16x8*>(&pw);
    oacc[0] = __builtin_amdgcn_mfma_f32_16x16x32_bf16(pf, vf[0], oacc[0], 0, 0, 0);
    oacc[1] = __builtin_amdgcn_mfma_f32_16x16x32_bf16(pf, vf[1], oacc[1], 0, 0, 0);
  }

  // ---- normalize + att tile to LDS ----
  {
    float s = ls;
    s += __shfl_xor(s, 16);
    s += __shfl_xor(s, 32);
    const float inv = 1.f / s;  // valid for q = lr
    #pragma unroll
    for (int r = 0; r < 4; ++r) {
      const float invr = __shfl(inv, lg * 4 + r);
      const int q = lg * 4 + r;
      #pragma unroll
      for (int tt = 0; tt < 2; ++tt)
        AT[q][h * 32 + tt * 16 + lr] = f2bf(oacc[tt][r] * invr);
    }
  }
  __syncthreads();

  // ---- out GEMM: wave h -> j in [h*32, h*32+32) ----
  f32x4 ao[2];
  ao[0] = f32x4{0.f, 0.f, 0.f, 0.f};
  ao[1] = f32x4{0.f, 0.f, 0.f, 0.f};
  #pragma unroll
  for (int kk = 0; kk < 4; ++kk) {
    const int c0 = kk * 32 + lg * 8;
    bf16x8 bfr = *reinterpret_cast<const bf16x8*>(&AT[lr][c0]);
    #pragma unroll
    for (int jt = 0; jt < 2; ++jt) {
      bf16x8 afr = cvt8(w_out + ((h * 2 + jt) * 16 + lr) * 128 + c0);
      ao[jt] = __builtin_amdgcn_mfma_f32_16x16x32_bf16(afr, bfr, ao[jt], 0, 0, 0);
    }
  }
  #pragma unroll
  for (int jt = 0; jt < 2; ++jt)
    #pragma unroll
    for (int r = 0; r < 4; ++r) {
      const int j = (h * 2 + jt) * 16 + lg * 4 + r;
      out[(b * 128 + j) * 4096 + q0 + lr] = ao[jt][r];
    }
}

// ---------------------------------------------------------------------------
extern "C" void kernel_launch(void* const* d_in, const int* in_sizes, int n_in,
                              void* d_out, int out_size, void* d_ws, size_t ws_size,
                              hipStream_t stream) {
  const float* x     = (const float*)d_in[0];
  const float* skip  = (const float*)d_in[1];
  const float* dw_q  = (const float*)d_in[2];
  const float* pw_q  = (const float*)d_in[3];
  const float* dw_kv = (const float*)d_in[4];
  const float* pw_kv = (const float*)d_in[5];
  const float* w_out = (const float*)d_in[6];
  float* out = (float*)d_out;
  (void)in_sizes; (void)n_in; (void)out_size; (void)ws_size;

  // workspace: dwQ bf16 [8][4096][128] @0 (8MB); kv16 f32 @8MB (2MB);
  //            Kp bf16 @10MB (2MB); Vp bf16 @12MB (2MB)
  char* wsb = (char*)d_ws;
  short* dwQ  = (short*)(wsb);
  float* kv16 = (float*)(wsb + (size_t)(8u << 20));
  short* Kp   = (short*)(wsb + (size_t)(10u << 20));
  short* Vp   = (short*)(wsb + (size_t)(12u << 20));

  k_dwq<<<dim3(64, 4, 8), dim3(256), 0, stream>>>(skip, dw_q, dwQ);
  k_kvgen<<<dim3(16, 2, 8), dim3(512), 0, stream>>>(x, dw_kv, pw_kv, kv16);
  k_resize<<<dim3(4096), dim3(256), 0, stream>>>(kv16, Kp, Vp);
  k_attn<<<dim3(256, 8), dim3(256), 0, stream>>>(dwQ, pw_q, Kp, Vp, w_out, out);
}